// Round 13
// baseline (564.562 us; speedup 1.0000x reference)
//
#include <hip/hip_runtime.h>
#include <hip/hip_bf16.h>
#include <cstdint>

constexpr int Mx = 8192;
constexpr int Kx = 4096;
constexpr int Nx = 16384;
constexpr long W_ELEMS = (long)Nx * Kx;      // 67108864
constexpr long X_ELEMS = (long)Mx * Kx;      // 33554432
constexpr int KB = Kx / 2;                   // 2048 packed fp4 bytes per row

typedef int v4i __attribute__((ext_vector_type(4)));
typedef int v8i __attribute__((ext_vector_type(8)));
typedef float v16f __attribute__((ext_vector_type(16)));

#define GLOBAL_AS(p) ((const __attribute__((address_space(1))) void*)(p))
#define LDS_AS(p)    ((__attribute__((address_space(3))) void*)(p))

template <int P> struct IC { static constexpr int value = P; };

// ---------------- Pass 1: sum |W| (deterministic two-level tree) ----------------
__global__ __launch_bounds__(256) void absum_kernel(const float4* __restrict__ W4,
                                                    double* __restrict__ partials) {
    int t = threadIdx.x;
    long base = (long)blockIdx.x * 8192;
    double s = 0.0;
#pragma unroll 4
    for (int i = 0; i < 32; ++i) {
        float4 v = W4[base + (long)i * 256 + t];
        s += (double)fabsf(v.x) + (double)fabsf(v.y) +
             (double)fabsf(v.z) + (double)fabsf(v.w);
    }
    __shared__ double sm[256];
    sm[t] = s;
    __syncthreads();
    for (int off = 128; off > 0; off >>= 1) {
        if (t < off) sm[t] += sm[t + off];
        __syncthreads();
    }
    if (t == 0) partials[blockIdx.x] = sm[0];
}

__global__ __launch_bounds__(256) void finalize_kernel(const double* __restrict__ partials,
                                                       float* __restrict__ thr) {
    int t = threadIdx.x;
    double s = 0.0;
#pragma unroll
    for (int i = 0; i < 8; ++i) s += partials[(long)i * 256 + t];
    __shared__ double sm[256];
    sm[t] = s;
    __syncthreads();
    for (int off = 128; off > 0; off >>= 1) {
        if (t < off) sm[t] += sm[t + off];
        __syncthreads();
    }
    if (t == 0) {
        double gamma = sm[0] / (double)W_ELEMS + 1e-6;
        *thr = (float)(0.5 * gamma);
    }
}

// fp4 e2m1 encode of ternary: +1 -> 0x2, -1 -> 0xA, 0 -> 0x0
__device__ __forceinline__ uint32_t enc_t(float v, float thr) {
    return (fabsf(v) > thr) ? ((v > 0.f) ? 0x2u : 0xAu) : 0x0u;
}

__device__ __forceinline__ uint32_t pack8(float4 a, float4 b, float thr) {
    return enc_t(a.x, thr)        | (enc_t(a.y, thr) << 4)  |
          (enc_t(a.z, thr) << 8)  | (enc_t(a.w, thr) << 12) |
          (enc_t(b.x, thr) << 16) | (enc_t(b.y, thr) << 20) |
          (enc_t(b.z, thr) << 24) | (enc_t(b.w, thr) << 28);
}

// ---------------- Pass 2: quantize W -> packed fp4 -----------------------------
__global__ __launch_bounds__(256) void quantw_kernel(const float4* __restrict__ W4,
                                                     uint32_t* __restrict__ out,
                                                     const float* __restrict__ thrp) {
    float thr = *thrp;
    long g = (long)blockIdx.x * 1024 + threadIdx.x;   // 8192 blocks * 4 iters
#pragma unroll
    for (int i = 0; i < 4; ++i, g += 256) {
        float4 a = W4[2 * g];
        float4 b = W4[2 * g + 1];
        out[g] = pack8(a, b, thr);
    }
}

// ---------------- Pass 3: binarize x -> packed fp4 sign ------------------------
__global__ __launch_bounds__(256) void quantx_kernel(const float4* __restrict__ X4,
                                                     uint32_t* __restrict__ out) {
    long g = (long)blockIdx.x * 1024 + threadIdx.x;   // 4096 blocks * 4 iters
#pragma unroll
    for (int i = 0; i < 4; ++i, g += 256) {
        float4 a = X4[2 * g];
        float4 b = X4[2 * g + 1];
        out[g] = pack8(a, b, 0.f);
    }
}

// ---------------- Pass 4: fp4 GEMM, 256^2 tile, mfma_scale 32x32x64 ------------
// r12 schedule with ONE barrier per PHASE (was per half-phase).  Safety:
//  - visibility of units {2tau, 2tau+1} for BOTH half-phases is established
//    by the end-of-(tau-1) barrier (its vmcnt(6) guarantees units <= 2tau+4
//    landed chip-wide before any wave enters phase tau);
//  - stage slots (2tau+5)&7, (2tau+6)&7 hold units 2tau-3, 2tau-2, last read
//    in phases tau-2 / tau-1, each separated from this phase's stage by >= 1
//    barrier;
//  - within-phase: read slots {2tau,2tau+1}&7 vs stage slots differ by
//    4..6 mod 8, never equal.
// Effect: h1's 6 ds_reads share a scheduling region with h0's 8 MFMAs ->
// compiler interleaves via fine lgkmcnt (within-wave ILP), and wave drift
// window doubles.  Register discipline: raw v4i fragments, convert-at-use
// (peak ~204 < 256; no spills -- watch WRITE_SIZE).
__global__ __launch_bounds__(512) void gemm_fp4(const uint8_t* __restrict__ A,
                                                const uint8_t* __restrict__ B,
                                                float* __restrict__ C) {
    __shared__ __align__(16) uint8_t smem[8 * 16384];   // 128 KiB

    const int t = threadIdx.x;
    const int l = t & 63;
    const int wid = t >> 6;
    const int wm = wid >> 2;          // 0..1
    const int wn = wid & 3;           // 0..3
    const int lr = l & 31;            // row within 32
    const int lh = l >> 5;            // k-chunk selector

    // Bijective XCD swizzle: 2048 wgs % 8 == 0.
    int wg = blockIdx.x;
    int sw = (wg & 7) * 256 + (wg >> 3);
    int bm = sw & 31;                 // 32 M-tiles
    int bn = sw >> 5;                 // 64 N-tiles
    const long m0 = (long)bm * 256;
    const long n0 = (long)bn * 256;

    // Staging: phys chunk cp holds row r = cp>>2, logical col c = (cp&3)^((r>>1)&3).
    const int r0s = t >> 2;
    const int cb0 = (((t & 3) ^ ((r0s >> 1) & 3)) << 4);
    const int voff0 = r0s * KB + cb0;            // shared by A and B panels
    const int voff1 = voff0 + 128 * KB;
    const uint8_t* Abase = A + m0 * (long)KB;    // uniform -> SGPR
    const uint8_t* Bbase = B + n0 * (long)KB;    // uniform -> SGPR
    const int lo0 = t * 16, lo1 = t * 16 + 8192;

    // ds_read offsets (swizzled), per k-half h: c = h*2 + lh.
    auto swz = [](int r, int c) {
        return r * 64 + ((c ^ ((r >> 1) & 3)) << 4);
    };
    int offA[2][4], offB[2][2];
#pragma unroll
    for (int h = 0; h < 2; ++h) {
#pragma unroll
        for (int mt = 0; mt < 4; ++mt)
            offA[h][mt] = swz(wm * 128 + mt * 32 + lr, h * 2 + lh);
#pragma unroll
        for (int nt = 0; nt < 2; ++nt)
            offB[h][nt] = swz(wn * 64 + nt * 32 + lr, h * 2 + lh);
    }

    v16f acc[4][2] = {};   // 128 regs (AGPR-eligible)

    // Prologue: issue units 0..4; wait units 0,1 landed (10-4=6 outstanding).
#pragma unroll
    for (int j = 0; j < 5; ++j) {
        int tj = j >> 1, slot = j;
        const uint8_t* s = (j & 1) ? Bbase : Abase;
        __builtin_amdgcn_global_load_lds(GLOBAL_AS(s + tj * 64 + voff0), LDS_AS(smem + slot * 16384 + lo0), 16, 0, 0);
        __builtin_amdgcn_global_load_lds(GLOBAL_AS(s + tj * 64 + voff1), LDS_AS(smem + slot * 16384 + lo1), 16, 0, 0);
    }
    asm volatile("s_waitcnt vmcnt(6)" ::: "memory");
    asm volatile("s_barrier" ::: "memory");

#pragma unroll 2
    for (int tau = 0; tau < 32; ++tau) {
        const int sA = (2 * tau) & 7;
        const int sB = sA + 1;

        auto half = [&](auto hc) {
            constexpr int h = decltype(hc)::value;
            // Raw v4i fragments (24 regs); convert to v8i at use.
            v4i ra[4], rb[2];
#pragma unroll
            for (int mt = 0; mt < 4; ++mt)
                ra[mt] = *(const v4i*)(smem + sA * 16384 + offA[h][mt]);
#pragma unroll
            for (int nt = 0; nt < 2; ++nt)
                rb[nt] = *(const v4i*)(smem + sB * 16384 + offB[h][nt]);
            // Stage unit j = 2*tau + h + 5 into slot j&7.
            {
                int j = 2 * tau + h + 5;
                if (j < 64) {
                    int tj = j >> 1, slot = j & 7;
                    const uint8_t* s = (j & 1) ? Bbase : Abase;
                    __builtin_amdgcn_global_load_lds(GLOBAL_AS(s + tj * 64 + voff0), LDS_AS(smem + slot * 16384 + lo0), 16, 0, 0);
                    __builtin_amdgcn_global_load_lds(GLOBAL_AS(s + tj * 64 + voff1), LDS_AS(smem + slot * 16384 + lo1), 16, 0, 0);
                }
            }
            v8i b80 = __builtin_shufflevector(rb[0], rb[0], 0, 1, 2, 3, -1, -1, -1, -1);
            v8i b81 = __builtin_shufflevector(rb[1], rb[1], 0, 1, 2, 3, -1, -1, -1, -1);
            __builtin_amdgcn_s_setprio(1);
#pragma unroll
            for (int mt = 0; mt < 4; ++mt) {
                v8i a8 = __builtin_shufflevector(ra[mt], ra[mt], 0, 1, 2, 3, -1, -1, -1, -1);
                acc[mt][0] = __builtin_amdgcn_mfma_scale_f32_32x32x64_f8f6f4(
                    a8, b80, acc[mt][0], 4, 4, 0, 0x7F7F7F7F, 0, 0x7F7F7F7F);
                acc[mt][1] = __builtin_amdgcn_mfma_scale_f32_32x32x64_f8f6f4(
                    a8, b81, acc[mt][1], 4, 4, 0, 0x7F7F7F7F, 0, 0x7F7F7F7F);
            }
            __builtin_amdgcn_s_setprio(0);
        };

        half(IC<0>{});   // no barrier between halves (proof in header)
        half(IC<1>{});

        if (tau <= 28)      asm volatile("s_waitcnt vmcnt(6)" ::: "memory");
        else if (tau == 29) asm volatile("s_waitcnt vmcnt(4)" ::: "memory");
        else if (tau == 30) asm volatile("s_waitcnt vmcnt(0)" ::: "memory");
        asm volatile("s_barrier" ::: "memory");
    }

    // Epilogue: 32x32 C/D layout col = lane&31, row = (reg&3)+8*(reg>>2)+4*(lane>>5).
#pragma unroll
    for (int mt = 0; mt < 4; ++mt) {
        long rbase = m0 + wm * 128 + mt * 32 + 4 * lh;
#pragma unroll
        for (int nt = 0; nt < 2; ++nt) {
            long gcol = n0 + wn * 64 + nt * 32 + lr;
#pragma unroll
            for (int r = 0; r < 16; ++r) {
                long grow = rbase + (r & 3) + 8 * (r >> 2);
                C[grow * Nx + gcol] = acc[mt][nt][r];
            }
        }
    }
}

extern "C" void kernel_launch(void* const* d_in, const int* in_sizes, int n_in,
                              void* d_out, int out_size, void* d_ws, size_t ws_size,
                              hipStream_t stream) {
    const float* x = (const float*)d_in[0];
    const float* weight = (const float*)d_in[1];
    float* out = (float*)d_out;

    // Workspace: xq 16 MB | wq 32 MB | partials 16 KB | thr
    uint8_t* xq = (uint8_t*)d_ws;
    uint8_t* wq = xq + X_ELEMS / 2;
    double* partials = (double*)((char*)d_ws + X_ELEMS / 2 + W_ELEMS / 2);
    float* thr = (float*)((char*)d_ws + X_ELEMS / 2 + W_ELEMS / 2 + 2048 * sizeof(double));

    absum_kernel<<<2048, 256, 0, stream>>>((const float4*)weight, partials);
    finalize_kernel<<<1, 256, 0, stream>>>(partials, thr);
    quantw_kernel<<<8192, 256, 0, stream>>>((const float4*)weight, (uint32_t*)wq, thr);
    quantx_kernel<<<4096, 256, 0, stream>>>((const float4*)x, (uint32_t*)xq);
    gemm_fp4<<<2048, 512, 0, stream>>>(xq, wq, out);
}

// Round 14
// 478.172 us; speedup vs baseline: 1.1807x; 1.1807x over previous
//
#include <hip/hip_runtime.h>
#include <hip/hip_bf16.h>
#include <cstdint>

constexpr int Mx = 8192;
constexpr int Kx = 4096;
constexpr int Nx = 16384;
constexpr long W_ELEMS = (long)Nx * Kx;      // 67108864
constexpr long X_ELEMS = (long)Mx * Kx;      // 33554432
constexpr int KB = Kx / 2;                   // 2048 packed fp4 bytes per row

typedef int v4i __attribute__((ext_vector_type(4)));
typedef int v8i __attribute__((ext_vector_type(8)));
typedef float v16f __attribute__((ext_vector_type(16)));

#define GLOBAL_AS(p) ((const __attribute__((address_space(1))) void*)(p))
#define LDS_AS(p)    ((__attribute__((address_space(3))) void*)(p))

template <int P> struct IC { static constexpr int value = P; };

// ---------------- Pass 1: sum |W| (deterministic two-level tree) ----------------
__global__ __launch_bounds__(256) void absum_kernel(const float4* __restrict__ W4,
                                                    double* __restrict__ partials) {
    int t = threadIdx.x;
    long base = (long)blockIdx.x * 8192;
    double s = 0.0;
#pragma unroll 4
    for (int i = 0; i < 32; ++i) {
        float4 v = W4[base + (long)i * 256 + t];
        s += (double)fabsf(v.x) + (double)fabsf(v.y) +
             (double)fabsf(v.z) + (double)fabsf(v.w);
    }
    __shared__ double sm[256];
    sm[t] = s;
    __syncthreads();
    for (int off = 128; off > 0; off >>= 1) {
        if (t < off) sm[t] += sm[t + off];
        __syncthreads();
    }
    if (t == 0) partials[blockIdx.x] = sm[0];
}

__global__ __launch_bounds__(256) void finalize_kernel(const double* __restrict__ partials,
                                                       float* __restrict__ thr) {
    int t = threadIdx.x;
    double s = 0.0;
#pragma unroll
    for (int i = 0; i < 8; ++i) s += partials[(long)i * 256 + t];
    __shared__ double sm[256];
    sm[t] = s;
    __syncthreads();
    for (int off = 128; off > 0; off >>= 1) {
        if (t < off) sm[t] += sm[t + off];
        __syncthreads();
    }
    if (t == 0) {
        double gamma = sm[0] / (double)W_ELEMS + 1e-6;
        *thr = (float)(0.5 * gamma);
    }
}

// fp4 e2m1 encode of ternary: +1 -> 0x2, -1 -> 0xA, 0 -> 0x0
__device__ __forceinline__ uint32_t enc_t(float v, float thr) {
    return (fabsf(v) > thr) ? ((v > 0.f) ? 0x2u : 0xAu) : 0x0u;
}

__device__ __forceinline__ uint32_t pack8(float4 a, float4 b, float thr) {
    return enc_t(a.x, thr)        | (enc_t(a.y, thr) << 4)  |
          (enc_t(a.z, thr) << 8)  | (enc_t(a.w, thr) << 12) |
          (enc_t(b.x, thr) << 16) | (enc_t(b.y, thr) << 20) |
          (enc_t(b.z, thr) << 24) | (enc_t(b.w, thr) << 28);
}

// ---------------- Pass 2: quantize W -> packed fp4 -----------------------------
__global__ __launch_bounds__(256) void quantw_kernel(const float4* __restrict__ W4,
                                                     uint32_t* __restrict__ out,
                                                     const float* __restrict__ thrp) {
    float thr = *thrp;
    long g = (long)blockIdx.x * 1024 + threadIdx.x;   // 8192 blocks * 4 iters
#pragma unroll
    for (int i = 0; i < 4; ++i, g += 256) {
        float4 a = W4[2 * g];
        float4 b = W4[2 * g + 1];
        out[g] = pack8(a, b, thr);
    }
}

// ---------------- Pass 3: binarize x -> packed fp4 sign ------------------------
__global__ __launch_bounds__(256) void quantx_kernel(const float4* __restrict__ X4,
                                                     uint32_t* __restrict__ out) {
    long g = (long)blockIdx.x * 1024 + threadIdx.x;   // 4096 blocks * 4 iters
#pragma unroll
    for (int i = 0; i < 4; ++i, g += 256) {
        float4 a = X4[2 * g];
        float4 b = X4[2 * g + 1];
        out[g] = pack8(a, b, 0.f);
    }
}

// ---------------- Pass 4: fp4 GEMM, 256^2 tile, mfma_scale 32x32x64 ------------
// r12 schedule verbatim (barrier per half-phase, proven 386 us / absmax 0),
// plus two schedule-preserving changes:
//  (1) 4x4 window swizzle inside each XCD chunk: window operand set = 4 A +
//      4 B panels = 4 MB = L2 size -> halves L3 staging traffic.
//  (2) staging lead 5 -> 7 units, vmcnt(6) -> vmcnt(10): 5 units in flight.
//      Safety: stage at (tau,h) writes slot (2tau+7+h)&7 which held unit
//      2tau-1+h, last read in the immediately preceding half-phase (>= 1
//      barrier separation); visibility: end-of-(tau-1) vmcnt(10) leaves
//      outstanding only units >= 2tau+2... i.e. units {2tau,2tau+1} landed.
//      Tail: vmcnt 10/8/4/0 at tau<=27/28/29/30.
__global__ __launch_bounds__(512) void gemm_fp4(const uint8_t* __restrict__ A,
                                                const uint8_t* __restrict__ B,
                                                float* __restrict__ C) {
    __shared__ __align__(16) uint8_t smem[8 * 16384];   // 128 KiB

    const int t = threadIdx.x;
    const int l = t & 63;
    const int wid = t >> 6;
    const int wm = wid >> 2;          // 0..1
    const int wn = wid & 3;           // 0..3
    const int lr = l & 31;            // row within 32
    const int lh = l >> 5;            // k-chunk selector

    // XCD swizzle (bijective, 2048 % 8 == 0) + 4x4 L2 window grouping.
    int wg = blockIdx.x;
    int sw = (wg & 7) * 256 + (wg >> 3);
    int chunk = sw >> 8;              // XCD id 0..7 (bn super-range)
    int local = sw & 255;
    int w = local >> 4;               // 16 windows of 4bm x 4bn
    int within = local & 15;
    int bm = (w & 7) * 4 + (within & 3);            // 0..31
    int bn = chunk * 8 + (w >> 3) * 4 + (within >> 2); // 0..63
    const long m0 = (long)bm * 256;
    const long n0 = (long)bn * 256;

    // Staging: phys chunk cp holds row r = cp>>2, logical col c = (cp&3)^((r>>1)&3).
    const int r0s = t >> 2;
    const int cb0 = (((t & 3) ^ ((r0s >> 1) & 3)) << 4);
    const int voff0 = r0s * KB + cb0;            // shared by A and B panels
    const int voff1 = voff0 + 128 * KB;
    const uint8_t* Abase = A + m0 * (long)KB;    // uniform -> SGPR
    const uint8_t* Bbase = B + n0 * (long)KB;    // uniform -> SGPR
    const int lo0 = t * 16, lo1 = t * 16 + 8192;

    // ds_read offsets (swizzled), per k-half h: c = h*2 + lh.
    auto swz = [](int r, int c) {
        return r * 64 + ((c ^ ((r >> 1) & 3)) << 4);
    };
    int offA[2][4], offB[2][2];
#pragma unroll
    for (int h = 0; h < 2; ++h) {
#pragma unroll
        for (int mt = 0; mt < 4; ++mt)
            offA[h][mt] = swz(wm * 128 + mt * 32 + lr, h * 2 + lh);
#pragma unroll
        for (int nt = 0; nt < 2; ++nt)
            offB[h][nt] = swz(wn * 64 + nt * 32 + lr, h * 2 + lh);
    }

    v16f acc[4][2] = {};   // 128 regs (AGPR-eligible)

    // Prologue: issue units 0..6; allow 5 units (10 loads) outstanding.
#pragma unroll
    for (int j = 0; j < 7; ++j) {
        int tj = j >> 1, slot = j;
        const uint8_t* s = (j & 1) ? Bbase : Abase;
        __builtin_amdgcn_global_load_lds(GLOBAL_AS(s + tj * 64 + voff0), LDS_AS(smem + slot * 16384 + lo0), 16, 0, 0);
        __builtin_amdgcn_global_load_lds(GLOBAL_AS(s + tj * 64 + voff1), LDS_AS(smem + slot * 16384 + lo1), 16, 0, 0);
    }
    asm volatile("s_waitcnt vmcnt(10)" ::: "memory");
    asm volatile("s_barrier" ::: "memory");

#pragma unroll 2
    for (int tau = 0; tau < 32; ++tau) {
        auto phase = [&](auto hc) {
            constexpr int h = decltype(hc)::value;
            const int sA = (2 * tau) & 7;
            const int sB = sA + 1;
            // Fragments in low half of v8i; high half undef (HW reads only
            // regs 0..3 for FMT=fp4 -- r4-r13 exactness proves it).
            v8i ar8[4], br8[2];
#pragma unroll
            for (int mt = 0; mt < 4; ++mt) {
                v4i v = *(const v4i*)(smem + sA * 16384 + offA[h][mt]);
                ar8[mt] = __builtin_shufflevector(v, v, 0, 1, 2, 3, -1, -1, -1, -1);
            }
#pragma unroll
            for (int nt = 0; nt < 2; ++nt) {
                v4i v = *(const v4i*)(smem + sB * 16384 + offB[h][nt]);
                br8[nt] = __builtin_shufflevector(v, v, 0, 1, 2, 3, -1, -1, -1, -1);
            }
            // Stage unit j = 2*tau + h + 7 into slot j&7.
            {
                int j = 2 * tau + h + 7;
                if (j < 64) {
                    int tj = j >> 1, slot = j & 7;
                    const uint8_t* s = (j & 1) ? Bbase : Abase;
                    __builtin_amdgcn_global_load_lds(GLOBAL_AS(s + tj * 64 + voff0), LDS_AS(smem + slot * 16384 + lo0), 16, 0, 0);
                    __builtin_amdgcn_global_load_lds(GLOBAL_AS(s + tj * 64 + voff1), LDS_AS(smem + slot * 16384 + lo1), 16, 0, 0);
                }
            }
            __builtin_amdgcn_s_setprio(1);
#pragma unroll
            for (int mt = 0; mt < 4; ++mt)
#pragma unroll
                for (int nt = 0; nt < 2; ++nt)
                    acc[mt][nt] = __builtin_amdgcn_mfma_scale_f32_32x32x64_f8f6f4(
                        ar8[mt], br8[nt], acc[mt][nt], 4, 4, 0, 0x7F7F7F7F, 0, 0x7F7F7F7F);
            __builtin_amdgcn_s_setprio(0);
            if constexpr (h == 1) {
                if (tau <= 27)      asm volatile("s_waitcnt vmcnt(10)" ::: "memory");
                else if (tau == 28) asm volatile("s_waitcnt vmcnt(8)" ::: "memory");
                else if (tau == 29) asm volatile("s_waitcnt vmcnt(4)" ::: "memory");
                else if (tau == 30) asm volatile("s_waitcnt vmcnt(0)" ::: "memory");
            }
            asm volatile("s_barrier" ::: "memory");
        };
        phase(IC<0>{});
        phase(IC<1>{});
    }

    // Epilogue: 32x32 C/D layout col = lane&31, row = (reg&3)+8*(reg>>2)+4*(lane>>5).
#pragma unroll
    for (int mt = 0; mt < 4; ++mt) {
        long rbase = m0 + wm * 128 + mt * 32 + 4 * lh;
#pragma unroll
        for (int nt = 0; nt < 2; ++nt) {
            long gcol = n0 + wn * 64 + nt * 32 + lr;
#pragma unroll
            for (int r = 0; r < 16; ++r) {
                long grow = rbase + (r & 3) + 8 * (r >> 2);
                C[grow * Nx + gcol] = acc[mt][nt][r];
            }
        }
    }
}

extern "C" void kernel_launch(void* const* d_in, const int* in_sizes, int n_in,
                              void* d_out, int out_size, void* d_ws, size_t ws_size,
                              hipStream_t stream) {
    const float* x = (const float*)d_in[0];
    const float* weight = (const float*)d_in[1];
    float* out = (float*)d_out;

    // Workspace: xq 16 MB | wq 32 MB | partials 16 KB | thr
    uint8_t* xq = (uint8_t*)d_ws;
    uint8_t* wq = xq + X_ELEMS / 2;
    double* partials = (double*)((char*)d_ws + X_ELEMS / 2 + W_ELEMS / 2);
    float* thr = (float*)((char*)d_ws + X_ELEMS / 2 + W_ELEMS / 2 + 2048 * sizeof(double));

    absum_kernel<<<2048, 256, 0, stream>>>((const float4*)weight, partials);
    finalize_kernel<<<1, 256, 0, stream>>>(partials, thr);
    quantw_kernel<<<8192, 256, 0, stream>>>((const float4*)weight, (uint32_t*)wq, thr);
    quantx_kernel<<<4096, 256, 0, stream>>>((const float4*)x, (uint32_t*)xq);
    gemm_fp4<<<2048, 512, 0, stream>>>(xq, wq, out);
}

// Round 16
// 466.249 us; speedup vs baseline: 1.2109x; 1.0256x over previous
//
#include <hip/hip_runtime.h>
#include <hip/hip_bf16.h>
#include <cstdint>

constexpr int Mx = 8192;
constexpr int Kx = 4096;
constexpr int Nx = 16384;
constexpr long W_ELEMS = (long)Nx * Kx;      // 67108864
constexpr long X_ELEMS = (long)Mx * Kx;      // 33554432
constexpr int KB = Kx / 2;                   // 2048 packed fp4 bytes per row

typedef int v4i __attribute__((ext_vector_type(4)));
typedef int v8i __attribute__((ext_vector_type(8)));
typedef float v16f __attribute__((ext_vector_type(16)));

#define GLOBAL_AS(p) ((const __attribute__((address_space(1))) void*)(p))
#define LDS_AS(p)    ((__attribute__((address_space(3))) void*)(p))

template <int P> struct IC { static constexpr int value = P; };

// ---------------- Pass 1: sum |W| (deterministic two-level tree) ----------------
__global__ __launch_bounds__(256) void absum_kernel(const float4* __restrict__ W4,
                                                    double* __restrict__ partials) {
    int t = threadIdx.x;
    long base = (long)blockIdx.x * 8192;
    double s = 0.0;
#pragma unroll 4
    for (int i = 0; i < 32; ++i) {
        float4 v = W4[base + (long)i * 256 + t];
        s += (double)fabsf(v.x) + (double)fabsf(v.y) +
             (double)fabsf(v.z) + (double)fabsf(v.w);
    }
    __shared__ double sm[256];
    sm[t] = s;
    __syncthreads();
    for (int off = 128; off > 0; off >>= 1) {
        if (t < off) sm[t] += sm[t + off];
        __syncthreads();
    }
    if (t == 0) partials[blockIdx.x] = sm[0];
}

__global__ __launch_bounds__(256) void finalize_kernel(const double* __restrict__ partials,
                                                       float* __restrict__ thr) {
    int t = threadIdx.x;
    double s = 0.0;
#pragma unroll
    for (int i = 0; i < 8; ++i) s += partials[(long)i * 256 + t];
    __shared__ double sm[256];
    sm[t] = s;
    __syncthreads();
    for (int off = 128; off > 0; off >>= 1) {
        if (t < off) sm[t] += sm[t + off];
        __syncthreads();
    }
    if (t == 0) {
        double gamma = sm[0] / (double)W_ELEMS + 1e-6;
        *thr = (float)(0.5 * gamma);
    }
}

// fp4 e2m1 encode of ternary: +1 -> 0x2, -1 -> 0xA, 0 -> 0x0
__device__ __forceinline__ uint32_t enc_t(float v, float thr) {
    return (fabsf(v) > thr) ? ((v > 0.f) ? 0x2u : 0xAu) : 0x0u;
}

__device__ __forceinline__ uint32_t pack8(float4 a, float4 b, float thr) {
    return enc_t(a.x, thr)        | (enc_t(a.y, thr) << 4)  |
          (enc_t(a.z, thr) << 8)  | (enc_t(a.w, thr) << 12) |
          (enc_t(b.x, thr) << 16) | (enc_t(b.y, thr) << 20) |
          (enc_t(b.z, thr) << 24) | (enc_t(b.w, thr) << 28);
}

// ---------------- Pass 2: quantize W -> packed fp4 -----------------------------
__global__ __launch_bounds__(256) void quantw_kernel(const float4* __restrict__ W4,
                                                     uint32_t* __restrict__ out,
                                                     const float* __restrict__ thrp) {
    float thr = *thrp;
    long g = (long)blockIdx.x * 1024 + threadIdx.x;   // 8192 blocks * 4 iters
#pragma unroll
    for (int i = 0; i < 4; ++i, g += 256) {
        float4 a = W4[2 * g];
        float4 b = W4[2 * g + 1];
        out[g] = pack8(a, b, thr);
    }
}

// ---------------- Pass 3: binarize x -> packed fp4 sign ------------------------
__global__ __launch_bounds__(256) void quantx_kernel(const float4* __restrict__ X4,
                                                     uint32_t* __restrict__ out) {
    long g = (long)blockIdx.x * 1024 + threadIdx.x;   // 4096 blocks * 4 iters
#pragma unroll
    for (int i = 0; i < 4; ++i, g += 256) {
        float4 a = X4[2 * g];
        float4 b = X4[2 * g + 1];
        out[g] = pack8(a, b, 0.f);
    }
}

// ---------------- Pass 4: fp4 GEMM, 256^2 tile, mfma_scale 32x32x64 ------------
// r14/r15 base with the WAR bug fixed: staging lead 7 -> 6.
//  BUG (r14/r15): lead 7 made the (tau,h=1) stage target slot (2tau+8)&7 =
//  sA -- the slot being READ this phase.  r14 survived only because reads
//  preceded the stage in program order (timing, not proof); r15's rolling
//  prefetch moved reads after the stage issue -> manifest corruption.
//  Lead L must satisfy (h+L) mod 8 not in {0,1}: L=6 gives stage slots
//  sA+6, sA+7 -- collision-free vs {sA, sA+1} chip-wide (per-half-phase
//  barriers keep all waves in the same half-phase), and the slot's previous
//  occupant (unit 2tau+h-2) was last read >= 1 barrier earlier.
//  Visibility: vmcnt(8) leaves units 2tau+4..2tau+7 in flight -> units
//  <= 2tau+3 landed before phase tau+1.  Tail vmcnt 8/4/0 at tau 28/29/30.
// Kept from r14/r15: L2 window swizzle (FETCH 540->197 MB, +50 us) and the
// B-first + rolling-A-prefetch read order (first MFMA waits on 3 reads, not
// 6; A1..A3 reads execute under MFMAs).
__global__ __launch_bounds__(512) void gemm_fp4(const uint8_t* __restrict__ A,
                                                const uint8_t* __restrict__ B,
                                                float* __restrict__ C) {
    __shared__ __align__(16) uint8_t smem[8 * 16384];   // 128 KiB

    const int t = threadIdx.x;
    const int l = t & 63;
    const int wid = t >> 6;
    const int wm = wid >> 2;          // 0..1
    const int wn = wid & 3;           // 0..3
    const int lr = l & 31;            // row within 32
    const int lh = l >> 5;            // k-chunk selector

    // XCD swizzle (bijective, 2048 % 8 == 0) + 4x4 L2 window grouping.
    int wg = blockIdx.x;
    int sw = (wg & 7) * 256 + (wg >> 3);
    int chunk = sw >> 8;              // XCD id 0..7 (bn super-range)
    int local = sw & 255;
    int w = local >> 4;               // 16 windows of 4bm x 4bn
    int within = local & 15;
    int bm = (w & 7) * 4 + (within & 3);               // 0..31
    int bn = chunk * 8 + (w >> 3) * 4 + (within >> 2); // 0..63
    const long m0 = (long)bm * 256;
    const long n0 = (long)bn * 256;

    // Staging: phys chunk cp holds row r = cp>>2, logical col c = (cp&3)^((r>>1)&3).
    const int r0s = t >> 2;
    const int cb0 = (((t & 3) ^ ((r0s >> 1) & 3)) << 4);
    const int voff0 = r0s * KB + cb0;            // shared by A and B panels
    const int voff1 = voff0 + 128 * KB;
    const uint8_t* Abase = A + m0 * (long)KB;    // uniform -> SGPR
    const uint8_t* Bbase = B + n0 * (long)KB;    // uniform -> SGPR
    const int lo0 = t * 16, lo1 = t * 16 + 8192;

    // ds_read offsets (swizzled), per k-half h: c = h*2 + lh.
    auto swz = [](int r, int c) {
        return r * 64 + ((c ^ ((r >> 1) & 3)) << 4);
    };
    int offA[2][4], offB[2][2];
#pragma unroll
    for (int h = 0; h < 2; ++h) {
#pragma unroll
        for (int mt = 0; mt < 4; ++mt)
            offA[h][mt] = swz(wm * 128 + mt * 32 + lr, h * 2 + lh);
#pragma unroll
        for (int nt = 0; nt < 2; ++nt)
            offB[h][nt] = swz(wn * 64 + nt * 32 + lr, h * 2 + lh);
    }

    v16f acc[4][2] = {};   // 128 regs (AGPR-eligible)

    // Prologue: issue units 0..5; wait until units 0,1 landed (8 outstanding).
#pragma unroll
    for (int j = 0; j < 6; ++j) {
        int tj = j >> 1, slot = j;
        const uint8_t* s = (j & 1) ? Bbase : Abase;
        __builtin_amdgcn_global_load_lds(GLOBAL_AS(s + tj * 64 + voff0), LDS_AS(smem + slot * 16384 + lo0), 16, 0, 0);
        __builtin_amdgcn_global_load_lds(GLOBAL_AS(s + tj * 64 + voff1), LDS_AS(smem + slot * 16384 + lo1), 16, 0, 0);
    }
    asm volatile("s_waitcnt vmcnt(8)" ::: "memory");
    asm volatile("s_barrier" ::: "memory");

#pragma unroll 2
    for (int tau = 0; tau < 32; ++tau) {
        auto phase = [&](auto hc) {
            constexpr int h = decltype(hc)::value;
            const int sA = (2 * tau) & 7;
            const int sB = sA + 1;
            // B first, then A0: first MFMA depends on only these 3 reads.
            v4i rb0 = *(const v4i*)(smem + sB * 16384 + offB[h][0]);
            v4i rb1 = *(const v4i*)(smem + sB * 16384 + offB[h][1]);
            v4i ra  = *(const v4i*)(smem + sA * 16384 + offA[h][0]);
            // Stage unit j = 2*tau + h + 6 into slot j&7 (slots sA+6, sA+7:
            // disjoint from this phase's read slots by construction).
            {
                int j = 2 * tau + h + 6;
                if (j < 64) {
                    int tj = j >> 1, slot = j & 7;
                    const uint8_t* s = (j & 1) ? Bbase : Abase;
                    __builtin_amdgcn_global_load_lds(GLOBAL_AS(s + tj * 64 + voff0), LDS_AS(smem + slot * 16384 + lo0), 16, 0, 0);
                    __builtin_amdgcn_global_load_lds(GLOBAL_AS(s + tj * 64 + voff1), LDS_AS(smem + slot * 16384 + lo1), 16, 0, 0);
                }
            }
            v8i b80 = __builtin_shufflevector(rb0, rb0, 0, 1, 2, 3, -1, -1, -1, -1);
            v8i b81 = __builtin_shufflevector(rb1, rb1, 0, 1, 2, 3, -1, -1, -1, -1);
            __builtin_amdgcn_s_setprio(1);
            // Rolling A prefetch: read A(mt+1) between MFMA pairs so the
            // lgkm wait before each pair leaves later reads outstanding.
            {
                v4i ra1 = *(const v4i*)(smem + sA * 16384 + offA[h][1]);
                v8i a8 = __builtin_shufflevector(ra, ra, 0, 1, 2, 3, -1, -1, -1, -1);
                acc[0][0] = __builtin_amdgcn_mfma_scale_f32_32x32x64_f8f6f4(
                    a8, b80, acc[0][0], 4, 4, 0, 0x7F7F7F7F, 0, 0x7F7F7F7F);
                acc[0][1] = __builtin_amdgcn_mfma_scale_f32_32x32x64_f8f6f4(
                    a8, b81, acc[0][1], 4, 4, 0, 0x7F7F7F7F, 0, 0x7F7F7F7F);
                ra = ra1;
            }
            {
                v4i ra2 = *(const v4i*)(smem + sA * 16384 + offA[h][2]);
                v8i a8 = __builtin_shufflevector(ra, ra, 0, 1, 2, 3, -1, -1, -1, -1);
                acc[1][0] = __builtin_amdgcn_mfma_scale_f32_32x32x64_f8f6f4(
                    a8, b80, acc[1][0], 4, 4, 0, 0x7F7F7F7F, 0, 0x7F7F7F7F);
                acc[1][1] = __builtin_amdgcn_mfma_scale_f32_32x32x64_f8f6f4(
                    a8, b81, acc[1][1], 4, 4, 0, 0x7F7F7F7F, 0, 0x7F7F7F7F);
                ra = ra2;
            }
            {
                v4i ra3 = *(const v4i*)(smem + sA * 16384 + offA[h][3]);
                v8i a8 = __builtin_shufflevector(ra, ra, 0, 1, 2, 3, -1, -1, -1, -1);
                acc[2][0] = __builtin_amdgcn_mfma_scale_f32_32x32x64_f8f6f4(
                    a8, b80, acc[2][0], 4, 4, 0, 0x7F7F7F7F, 0, 0x7F7F7F7F);
                acc[2][1] = __builtin_amdgcn_mfma_scale_f32_32x32x64_f8f6f4(
                    a8, b81, acc[2][1], 4, 4, 0, 0x7F7F7F7F, 0, 0x7F7F7F7F);
                ra = ra3;
            }
            {
                v8i a8 = __builtin_shufflevector(ra, ra, 0, 1, 2, 3, -1, -1, -1, -1);
                acc[3][0] = __builtin_amdgcn_mfma_scale_f32_32x32x64_f8f6f4(
                    a8, b80, acc[3][0], 4, 4, 0, 0x7F7F7F7F, 0, 0x7F7F7F7F);
                acc[3][1] = __builtin_amdgcn_mfma_scale_f32_32x32x64_f8f6f4(
                    a8, b81, acc[3][1], 4, 4, 0, 0x7F7F7F7F, 0, 0x7F7F7F7F);
            }
            __builtin_amdgcn_s_setprio(0);
            if constexpr (h == 1) {
                if (tau <= 28)      asm volatile("s_waitcnt vmcnt(8)" ::: "memory");
                else if (tau == 29) asm volatile("s_waitcnt vmcnt(4)" ::: "memory");
                else if (tau == 30) asm volatile("s_waitcnt vmcnt(0)" ::: "memory");
            }
            asm volatile("s_barrier" ::: "memory");
        };
        phase(IC<0>{});
        phase(IC<1>{});
    }

    // Epilogue: 32x32 C/D layout col = lane&31, row = (reg&3)+8*(reg>>2)+4*(lane>>5).
#pragma unroll
    for (int mt = 0; mt < 4; ++mt) {
        long rbase = m0 + wm * 128 + mt * 32 + 4 * lh;
#pragma unroll
        for (int nt = 0; nt < 2; ++nt) {
            long gcol = n0 + wn * 64 + nt * 32 + lr;
#pragma unroll
            for (int r = 0; r < 16; ++r) {
                long grow = rbase + (r & 3) + 8 * (r >> 2);
                C[grow * Nx + gcol] = acc[mt][nt][r];
            }
        }
    }
}

extern "C" void kernel_launch(void* const* d_in, const int* in_sizes, int n_in,
                              void* d_out, int out_size, void* d_ws, size_t ws_size,
                              hipStream_t stream) {
    const float* x = (const float*)d_in[0];
    const float* weight = (const float*)d_in[1];
    float* out = (float*)d_out;

    // Workspace: xq 16 MB | wq 32 MB | partials 16 KB | thr
    uint8_t* xq = (uint8_t*)d_ws;
    uint8_t* wq = xq + X_ELEMS / 2;
    double* partials = (double*)((char*)d_ws + X_ELEMS / 2 + W_ELEMS / 2);
    float* thr = (float*)((char*)d_ws + X_ELEMS / 2 + W_ELEMS / 2 + 2048 * sizeof(double));

    absum_kernel<<<2048, 256, 0, stream>>>((const float4*)weight, partials);
    finalize_kernel<<<1, 256, 0, stream>>>(partials, thr);
    quantw_kernel<<<8192, 256, 0, stream>>>((const float4*)weight, (uint32_t*)wq, thr);
    quantx_kernel<<<4096, 256, 0, stream>>>((const float4*)x, (uint32_t*)xq);
    gemm_fp4<<<2048, 512, 0, stream>>>(xq, wq, out);
}